// Round 6
// baseline (202.261 us; speedup 1.0000x reference)
//
#include <hip/hip_runtime.h>
#include <math.h>

// ---------------------------------------------------------------------------
// CSPN_Propagate — MI355X. Round 5 (resubmit; previous run died on an
// unresponsive container before executing):
//  * conv rewritten: 8 px/thread (2 rows x 4 cols), weights transposed into
//    LDS [ci][ky][kx][o] once per block -> uniform ds_read_b128 broadcasts in
//    the inner loop (no per-iteration scalar-load stalls), float4 feature
//    loads with 4-row reuse. Round-4 conv was 130 us @ VALUBusy 55% (3.2x the
//    41 us FMA floor) -> issue/latency bound on weight fetch + addr calc.
//  * prep / cspn3 / launch structure identical to round 4 (passed, ~60 us).
// ---------------------------------------------------------------------------

#define B 16
#define FH 256
#define FW 512
#define TH 32
#define TW 32
#define HALO 3
#define LD 38
#define GD 36
#define MAXC 6

// ------------------------- prep: all raw buffers ----------------------------
__global__ __launch_bounds__(256) void prep_all_kernel(
    const float* __restrict__ gt, const float* __restrict__ blur,
    const float* __restrict__ rgb, float* __restrict__ r0,
    float* __restrict__ r1, float* __restrict__ r2, float* __restrict__ r3) {
  int idx = blockIdx.x * blockDim.x + threadIdx.x;
  const int n0 = B * 96 * 192, n1 = B * 128 * 256, n2 = B * 160 * 320,
            n3 = B * 192 * 384;
  float* dst;
  int h, w, hs, ws;
  if (idx < n0) {
    dst = r0; h = 96; w = 192; hs = 80; ws = 160;
  } else if (idx < n0 + n1) {
    idx -= n0; dst = r1; h = 128; w = 256; hs = 64; ws = 128;
  } else if (idx < n0 + n1 + n2) {
    idx -= n0 + n1; dst = r2; h = 160; w = 320; hs = 48; ws = 96;
  } else if (idx < n0 + n1 + n2 + n3) {
    idx -= n0 + n1 + n2; dst = r3; h = 192; w = 384; hs = 32; ws = 64;
  } else {
    return;
  }
  int x = idx % w;
  int t = idx / w;
  int y = t % h;
  int b = t / h;
  size_t g = (size_t)b * FH * FW + (size_t)(hs + y) * FW + (ws + x);
  float dep = rgb[((size_t)b * 3) * FH * FW + (size_t)(hs + y) * FW + (ws + x)];
  if (dst == r0) {
    float gv = gt[g];
    float s = gv / blur[g];
    float dl = (s > 1.2f || s < 0.8f) ? 0.0f : gv;
    dst[idx] = (dl > 0.0f) ? dl : dep;
  } else {
    dst[idx] = dep;
  }
}

// ------------------- conv block + ELU, all 4 stages, one dispatch -----------
// 8 px/thread (2 rows x 4 cols); weights in LDS [ci][ky][kx][o].
__global__ __launch_bounds__(256) void conv_all_kernel(
    const float* __restrict__ feat, const float* __restrict__ w0c,
    const float* __restrict__ b0c, float* __restrict__ g0,
    const float* __restrict__ w1c, const float* __restrict__ b1c,
    float* __restrict__ g1, const float* __restrict__ w2c,
    const float* __restrict__ b2c, float* __restrict__ g2,
    const float* __restrict__ w3c, const float* __restrict__ b3c,
    float* __restrict__ g3) {
  __shared__ __align__(16) float lw[16 * 9 * 8];  // [ci][ky*3+kx][o]
  __shared__ float lb[8];

  int bid = blockIdx.x;
  int h, w, base;
  const float *wgt, *bias;
  float* guid;
  if (bid < 144)       { h = 96;  w = 192; wgt = w0c; bias = b0c; guid = g0; base = 0; }
  else if (bid < 400)  { h = 128; w = 256; wgt = w1c; bias = b1c; guid = g1; base = 144; }
  else if (bid < 800)  { h = 160; w = 320; wgt = w2c; bias = b2c; guid = g2; base = 400; }
  else                 { h = 192; w = 384; wgt = w3c; bias = b3c; guid = g3; base = 800; }
  int hs = (FH - h) >> 1, wss = (FW - w) >> 1;

  // transpose weights into LDS: lw[(ci*9+r)*8+o] = wgt[(o*16+ci)*9+r]
  for (int e = threadIdx.x; e < 1152; e += 256) {
    int o = e & 7;
    int pos = e >> 3;          // ci*9 + r
    int ci = pos / 9, r = pos % 9;
    lw[e] = wgt[(o * 16 + ci) * 9 + r];
  }
  if (threadIdx.x < 8) lb[threadIdx.x] = bias[threadIdx.x];
  __syncthreads();

  int idx = (bid - base) * 256 + threadIdx.x;
  int wq = w >> 2;
  int h2r = h >> 1;
  int x = (idx % wq) << 2;
  int t = idx / wq;
  int y = (t % h2r) << 1;     // output rows y, y+1
  int b = t / h2r;

  // 4 input rows: y-1 .. y+2, reflect-clamped within the crop
  int ry[4];
#pragma unroll
  for (int k = 0; k < 4; ++k) {
    int cy = y + k - 1;
    cy = (cy < 0) ? 1 : ((cy >= h) ? (h - 2) : cy);
    ry[k] = hs + cy;
  }
  int xm1 = wss + ((x == 0) ? 1 : x - 1);
  int xp4 = wss + ((x + 4 >= w) ? w - 2 : x + 4);

  float acc[8][8];
#pragma unroll
  for (int o = 0; o < 8; ++o) {
    float bv = lb[o];
#pragma unroll
    for (int p = 0; p < 8; ++p) acc[o][p] = bv;
  }

  const float* fb = feat + (size_t)b * 16 * FH * FW;
  for (int ci = 0; ci < 16; ++ci) {
    const float* fc = fb + (size_t)ci * FH * FW;
    float v[4][6];
#pragma unroll
    for (int r = 0; r < 4; ++r) {
      const float* frow = fc + (size_t)ry[r] * FW;
      float4 m = *(const float4*)(frow + wss + x);
      v[r][0] = frow[xm1];
      v[r][1] = m.x; v[r][2] = m.y; v[r][3] = m.z; v[r][4] = m.w;
      v[r][5] = frow[xp4];
    }
    const float* wc = lw + ci * 72;
#pragma unroll
    for (int ky = 0; ky < 3; ++ky) {
#pragma unroll
      for (int kx = 0; kx < 3; ++kx) {
        float4 wa = *(const float4*)(wc + (ky * 3 + kx) * 8);
        float4 wb = *(const float4*)(wc + (ky * 3 + kx) * 8 + 4);
#pragma unroll
        for (int r = 0; r < 2; ++r) {
#pragma unroll
          for (int p = 0; p < 4; ++p) {
            float fv = v[ky + r][kx + p];
            int q = r * 4 + p;
            acc[0][q] = fmaf(fv, wa.x, acc[0][q]);
            acc[1][q] = fmaf(fv, wa.y, acc[1][q]);
            acc[2][q] = fmaf(fv, wa.z, acc[2][q]);
            acc[3][q] = fmaf(fv, wa.w, acc[3][q]);
            acc[4][q] = fmaf(fv, wb.x, acc[4][q]);
            acc[5][q] = fmaf(fv, wb.y, acc[5][q]);
            acc[6][q] = fmaf(fv, wb.z, acc[6][q]);
            acc[7][q] = fmaf(fv, wb.w, acc[7][q]);
          }
        }
      }
    }
  }

  size_t hw = (size_t)h * w;
  float* gb = guid + (size_t)b * 8 * hw + (size_t)y * w + x;
#pragma unroll
  for (int o = 0; o < 8; ++o) {
#pragma unroll
    for (int r = 0; r < 2; ++r) {
      float a0 = acc[o][r * 4 + 0], a1 = acc[o][r * 4 + 1],
            a2 = acc[o][r * 4 + 2], a3 = acc[o][r * 4 + 3];
      float4 rv;
      rv.x = (a0 > 0.0f) ? a0 : expm1f(a0);
      rv.y = (a1 > 0.0f) ? a1 : expm1f(a1);
      rv.z = (a2 > 0.0f) ? a2 : expm1f(a2);
      rv.w = (a3 > 0.0f) ? a3 : expm1f(a3);
      *(float4*)(gb + (size_t)o * hw + (size_t)r * w) = rv;
    }
  }
}

// ---------------- fused CSPN x3 with register gates -------------------------
__global__ __launch_bounds__(256) void cspn3_kernel(
    const float* __restrict__ guid, const float* __restrict__ raw,
    const float* __restrict__ rgb, float* __restrict__ dst, int h, int w,
    int hs, int wss, int h2, int w2, int ph, int pw, int last) {
  __shared__ float sraw[LD * LD];
  __shared__ float s0[LD * LD];
  __shared__ float s1[LD * LD];

  int tpw = w / TW, tph = h / TH;
  int tile = blockIdx.x;
  int tx = tile % tpw;
  int t2 = tile / tpw;
  int ty = t2 % tph;
  int b = t2 / tph;
  int oy = ty * TH - HALO, ox = tx * TW - HALO;
  int tid = threadIdx.x;

  const float* rb = raw + (size_t)b * h * w;

  for (int e = tid; e < LD * LD; e += 256) {
    int r = e / LD, c = e % LD;
    int gy = oy + r, gx = ox + c;
    bool in = (gy >= 0 && gy < h && gx >= 0 && gx < w);
    sraw[e] = in ? rb[(size_t)gy * w + gx] : 0.0f;
  }
  __syncthreads();

  const int dy8[8] = {1, 1, 1, 0, 0, -1, -1, -1};
  const int dx8[8] = {1, 0, -1, 1, -1, 1, 0, -1};
  const int off8[8] = {LD + 1, LD, LD - 1, 1, -1, -LD + 1, -LD, -LD - 1};

  const float* gb = guid + (size_t)b * 8 * h * w;
  float cg[MAXC][8];
  float r0[MAXC];
  int adr[MAXC];
#pragma unroll
  for (int ch = 0; ch < MAXC; ++ch) {
    int p = tid + ch * 256;
    bool ok = p < GD * GD;
    int pp = ok ? p : 0;
    int py = pp / GD + 1, px = pp % GD + 1;
    adr[ch] = py * LD + px;
    int gy = oy + py, gx = ox + px;
    bool in = ok && gy >= 0 && gy < h && gx >= 0 && gx < w;
    float wsum = 0.0f, asum = 0.0f;
    float g[8];
#pragma unroll
    for (int k = 0; k < 8; ++k) {
      int ny = gy + dy8[k], nx = gx + dx8[k];
      bool nin = ok && ny >= 0 && ny < h && nx >= 0 && nx < w;
      float gk = nin ? gb[(size_t)k * h * w + (size_t)ny * w + nx] : 0.0f;
      g[k] = gk;
      wsum += gk;
      asum += fabsf(gk);
    }
    float inv = in ? (1.0f / asum) : 0.0f;
#pragma unroll
    for (int k = 0; k < 8; ++k) cg[ch][k] = g[k] * inv;
    r0[ch] = in ? (1.0f - wsum * inv) * sraw[adr[ch]] : 0.0f;
  }

#pragma unroll
  for (int ch = 0; ch < MAXC; ++ch) {
    int p = tid + ch * 256;
    if (p < GD * GD) {
      float v = r0[ch];
#pragma unroll
      for (int k = 0; k < 8; ++k) v += cg[ch][k] * sraw[adr[ch] + off8[k]];
      s0[adr[ch]] = v;
    }
  }
  __syncthreads();

#pragma unroll
  for (int ch = 0; ch < MAXC; ++ch) {
    int p = tid + ch * 256;
    if (p < GD * GD) {
      int py = p / GD + 1, px = p % GD + 1;
      if (py >= 2 && py <= 35 && px >= 2 && px <= 35) {
        float v = r0[ch];
#pragma unroll
        for (int k = 0; k < 8; ++k) v += cg[ch][k] * s0[adr[ch] + off8[k]];
        s1[adr[ch]] = v;
      }
    }
  }
  __syncthreads();

#pragma unroll
  for (int ch = 0; ch < MAXC; ++ch) {
    int p = tid + ch * 256;
    if (p < GD * GD) {
      int py = p / GD + 1, px = p % GD + 1;
      if (py >= 3 && py <= 34 && px >= 3 && px <= 34) {
        float v = r0[ch];
#pragma unroll
        for (int k = 0; k < 8; ++k) v += cg[ch][k] * s1[adr[ch] + off8[k]];
        float dl = fminf(fmaxf(v, 0.0f), 1.0f);
        int gy = oy + py, gx = ox + px;
        if (last) {
          dst[((size_t)b * h + gy) * w + gx] = dl;
        } else {
          float dep = rgb[((size_t)b * 3) * FH * FW + (size_t)(hs + gy) * FW +
                          (wss + gx)];
          dst[((size_t)b * h2 + (gy + ph)) * w2 + (gx + pw)] =
              (dl > 0.0f) ? dl : dep;
        }
      }
    }
  }
}

// ---------------------------------------------------------------------------
extern "C" void kernel_launch(void* const* d_in, const int* in_sizes, int n_in,
                              void* d_out, int out_size, void* d_ws,
                              size_t ws_size, hipStream_t stream) {
  (void)in_sizes; (void)n_in; (void)out_size; (void)ws_size;
  const float* feat = (const float*)d_in[0];
  const float* blur = (const float*)d_in[1];
  const float* gt = (const float*)d_in[2];
  const float* rgb = (const float*)d_in[3];
  const float* W[4] = {(const float*)d_in[5], (const float*)d_in[7],
                       (const float*)d_in[9], (const float*)d_in[11]};
  const float* Bs[4] = {(const float*)d_in[6], (const float*)d_in[8],
                        (const float*)d_in[10], (const float*)d_in[12]};
  float* out = (float*)d_out;

  float* G0 = (float*)d_ws;
  float* G1 = G0 + (size_t)B * 8 * 96 * 192;
  float* G2 = G1 + (size_t)B * 8 * 128 * 256;
  float* G3 = G2 + (size_t)B * 8 * 160 * 320;
  float* RAW[4];
  RAW[0] = G3 + (size_t)B * 8 * 192 * 384;
  RAW[1] = RAW[0] + (size_t)B * 96 * 192;
  RAW[2] = RAW[1] + (size_t)B * 128 * 256;
  RAW[3] = RAW[2] + (size_t)B * 160 * 320;
  float* G[4] = {G0, G1, G2, G3};

  const int CH[4] = {96, 128, 160, 192};
  const int CW[4] = {192, 256, 320, 384};

  {
    int n = B * (96 * 192 + 128 * 256 + 160 * 320 + 192 * 384);
    prep_all_kernel<<<(n + 255) / 256, 256, 0, stream>>>(gt, blur, rgb, RAW[0],
                                                         RAW[1], RAW[2],
                                                         RAW[3]);
  }

  conv_all_kernel<<<1376, 256, 0, stream>>>(feat, W[0], Bs[0], G0, W[1], Bs[1],
                                            G1, W[2], Bs[2], G2, W[3], Bs[3],
                                            G3);

  for (int i = 0; i < 4; ++i) {
    int h = CH[i], w = CW[i];
    int hs = (FH - h) / 2, wss = (FW - w) / 2;
    int ntiles = B * (h / TH) * (w / TW);
    if (i < 3) {
      int h2 = CH[i + 1], w2 = CW[i + 1];
      int ph = (h2 - h) / 2, pw = (w2 - w) / 2;
      cspn3_kernel<<<ntiles, 256, 0, stream>>>(G[i], RAW[i], rgb, RAW[i + 1],
                                               h, w, hs, wss, h2, w2, ph, pw,
                                               0);
    } else {
      cspn3_kernel<<<ntiles, 256, 0, stream>>>(G[i], RAW[i], rgb, out, h, w,
                                               hs, wss, h, w, 0, 0, 1);
    }
  }
}